// Round 6
// baseline (295.030 us; speedup 1.0000x reference)
//
#include <hip/hip_runtime.h>
#include <cstddef>
#include <math.h>

#define L_DIM 2048
#define C_DIM 512
#define CQ_DIM 64
#define B_DIM 8

typedef _Float16 f16x8 __attribute__((ext_vector_type(8)));
typedef float f32x4 __attribute__((ext_vector_type(4)));

__device__ __forceinline__ unsigned short f2h(float f) {
    union { _Float16 h; unsigned short u; } v;
    v.h = (_Float16)f;
    return v.u;
}

// ---------------------------------------------------------------------------
// prep_w: Wq/Wk/Wv (fp32 [co][ci][3]) -> Wh fp16 [t][640co][512ci]
// ---------------------------------------------------------------------------
__global__ __launch_bounds__(256) void prep_w(const float* __restrict__ Wq,
                                              const float* __restrict__ Wk,
                                              const float* __restrict__ Wv,
                                              unsigned short* __restrict__ Wh) {
    const int idx = blockIdx.x * 256 + threadIdx.x;
    const int ci = idx & 511;
    const int co = (idx >> 9) % 640;
    const int t  = idx / (640 * 512);
    float w;
    if (co < 64)       w = Wq[(size_t)co * 1536 + ci * 3 + t];
    else if (co < 128) w = Wk[(size_t)(co - 64) * 1536 + ci * 3 + t];
    else               w = Wv[(size_t)(co - 128) * 1536 + ci * 3 + t];
    Wh[idx] = f2h(w);
}

// ---------------------------------------------------------------------------
// prep_x: x fp32 [b][ci][l] -> xT fp16 [b][l][512ci]. 64ci x 64l tile per block.
// ---------------------------------------------------------------------------
__global__ __launch_bounds__(256) void prep_x(const float* __restrict__ x,
                                              unsigned short* __restrict__ xT) {
    const int l0  = blockIdx.x * 64;
    const int ci0 = blockIdx.y * 64;
    const int b   = blockIdx.z;

    __shared__ float xs[64][68];
    const int tid = threadIdx.x;
    const float* xb = x + ((size_t)b * C_DIM + ci0) * L_DIM;

    for (int idx = tid; idx < 64 * 16; idx += 256) {
        int ci = idx >> 4, lq = idx & 15;
        *(float4*)&xs[ci][lq * 4] = *(const float4*)&xb[(size_t)ci * L_DIM + l0 + lq * 4];
    }
    __syncthreads();

    unsigned short* ob = xT + ((size_t)b * L_DIM + l0) * C_DIM + ci0;
    for (int idx = tid; idx < 64 * 8; idx += 256) {
        int l = idx >> 3, c8 = idx & 7;
        ushort4 r0, r1;
        r0.x = f2h(xs[c8 * 8 + 0][l]); r0.y = f2h(xs[c8 * 8 + 1][l]);
        r0.z = f2h(xs[c8 * 8 + 2][l]); r0.w = f2h(xs[c8 * 8 + 3][l]);
        r1.x = f2h(xs[c8 * 8 + 4][l]); r1.y = f2h(xs[c8 * 8 + 5][l]);
        r1.z = f2h(xs[c8 * 8 + 6][l]); r1.w = f2h(xs[c8 * 8 + 7][l]);
        *(ushort4*)&ob[(size_t)l * C_DIM + c8 * 8] = r0;
        *(ushort4*)&ob[(size_t)l * C_DIM + c8 * 8 + 4] = r1;
    }
}

// ---------------------------------------------------------------------------
// conv_all: out[co,l] = sum_t sum_ci Wh[t][co][ci] * x[ci][l+t-1] via MFMA.
// ---------------------------------------------------------------------------
__global__ __launch_bounds__(256) void conv_all(const unsigned short* __restrict__ Wh,
                                                const unsigned short* __restrict__ xT,
                                                unsigned short* __restrict__ qT,
                                                unsigned short* __restrict__ kT,
                                                unsigned short* __restrict__ vB) {
    const int l0  = blockIdx.x * 128;
    const int co0 = blockIdx.y * 64;
    const int b   = blockIdx.z;

    __shared__ unsigned short As[3][64][40];
    __shared__ unsigned short Bs[130][40];

    const int tid  = threadIdx.x;
    const int lane = tid & 63, w = tid >> 6;
    const int ln15 = lane & 15, quad = lane >> 4;

    const int co_w = (w & 1) * 32;
    const int l_w  = (w >> 1) * 64;

    const unsigned short* xb = xT + (size_t)b * L_DIM * C_DIM;

    f32x4 acc[2][4] = {};

    for (int ci0 = 0; ci0 < C_DIM; ci0 += 32) {
        __syncthreads();
        for (int idx = tid; idx < 768; idx += 256) {
            int t = idx >> 8, co = (idx >> 2) & 63, c8 = idx & 3;
            *(float4*)&As[t][co][c8 * 8] =
                *(const float4*)&Wh[(((size_t)t * 640) + co0 + co) * C_DIM + ci0 + c8 * 8];
        }
        for (int idx = tid; idx < 520; idx += 256) {
            int la = idx >> 2, c8 = idx & 3;
            int l = l0 - 1 + la;
            float4 vx = {0.f, 0.f, 0.f, 0.f};
            if (l >= 0 && l < L_DIM)
                vx = *(const float4*)&xb[(size_t)l * C_DIM + ci0 + c8 * 8];
            *(float4*)&Bs[la][c8 * 8] = vx;
        }
        __syncthreads();

#pragma unroll
        for (int t = 0; t < 3; t++) {
            f16x8 a[2], bfr[4];
#pragma unroll
            for (int ct = 0; ct < 2; ct++)
                a[ct] = *(const f16x8*)&As[t][co_w + ct * 16 + ln15][quad * 8];
#pragma unroll
            for (int lt = 0; lt < 4; lt++)
                bfr[lt] = *(const f16x8*)&Bs[l_w + lt * 16 + ln15 + t][quad * 8];
#pragma unroll
            for (int ct = 0; ct < 2; ct++)
#pragma unroll
                for (int lt = 0; lt < 4; lt++)
                    acc[ct][lt] = __builtin_amdgcn_mfma_f32_16x16x32_f16(a[ct], bfr[lt], acc[ct][lt], 0, 0, 0);
        }
    }

    if (co0 < 128) {
        unsigned short* dst = (co0 == 0 ? qT : kT) + (size_t)b * L_DIM * CQ_DIM;
#pragma unroll
        for (int ct = 0; ct < 2; ct++)
#pragma unroll
            for (int lt = 0; lt < 4; lt++) {
                const int l = l0 + l_w + lt * 16 + ln15;
                ushort4 r;
                r.x = f2h(acc[ct][lt][0]); r.y = f2h(acc[ct][lt][1]);
                r.z = f2h(acc[ct][lt][2]); r.w = f2h(acc[ct][lt][3]);
                *(ushort4*)&dst[(size_t)l * CQ_DIM + co_w + ct * 16 + quad * 4] = r;
            }
    } else {
        unsigned short* dst = vB + ((size_t)b * C_DIM + (co0 - 128)) * L_DIM;
#pragma unroll
        for (int ct = 0; ct < 2; ct++)
#pragma unroll
            for (int lt = 0; lt < 4; lt++) {
                const int l = l0 + l_w + lt * 16 + ln15;
#pragma unroll
                for (int r = 0; r < 4; r++) {
                    const int co = co_w + ct * 16 + quad * 4 + r;
                    dst[(size_t)co * L_DIM + l] = f2h(acc[ct][lt][r]);
                }
            }
    }
}

// ---------------------------------------------------------------------------
// Fused attention, online softmax. K-fragments hoisted to registers (loop-
// invariant); the kT staging LDS is reused (aliased) as the pps buffer ->
// 46.5 KB LDS -> 3 blocks/CU.
// Block: 256 threads (4 waves), out tile 128co x 128j. Grid (16 j, 4 co, 8 b).
// ---------------------------------------------------------------------------
#define LOG2E 1.44269504088896f

__global__ __launch_bounds__(256) void pv_k(const unsigned short* __restrict__ qT,
                                            const unsigned short* __restrict__ kT,
                                            const unsigned short* __restrict__ vB,
                                            const float* __restrict__ gamma,
                                            float* __restrict__ out) {
    const int j0  = blockIdx.x * 128;
    const int co0 = blockIdx.y * 128;
    const int b   = blockIdx.z;

    // pps aliases the kT staging area (kT only needed before the K-loop)
    __shared__ unsigned short pps[128 * 72];  // init: [j][c] kT stage; loop: [j][i] p
    __shared__ unsigned short qTs[64 * 72];   // [i][c]
    __shared__ unsigned short vvs[128 * 72];  // [co][i]
    __shared__ float al_s[128];               // per-iter alpha[j]; reused for l at end

    const int tid = threadIdx.x;
    const int lane = tid & 63, w = tid >> 6;
    const int ln15 = lane & 15, quad = lane >> 4;

    const unsigned short* qb = qT + (size_t)b * L_DIM * CQ_DIM;
    const unsigned short* kb = kT + (size_t)b * L_DIM * CQ_DIM;
    const unsigned short* vb = vB + (size_t)b * C_DIM * L_DIM;

    const int wco = (w >> 1) * 64;  // PV phase: wave's co range within 128
    const int wj  = (w & 1) * 64;   // PV phase: wave's j range within 128
    const int sj  = w * 32;         // scores phase: wave's j range within 128

    // ---- stage kT once, hoist this wave's K-fragments into registers ----
    for (int idx = tid; idx < 128 * 8; idx += 256) {
        int r = idx >> 3, c8 = idx & 7;
        *(float4*)&pps[r * 72 + c8 * 8] = *(const float4*)&kb[(size_t)(j0 + r) * CQ_DIM + c8 * 8];
    }
    __syncthreads();
    f16x8 kfr[2][2];   // [jt][cc]
#pragma unroll
    for (int jt = 0; jt < 2; jt++)
#pragma unroll
        for (int cc = 0; cc < 2; cc++)
            kfr[jt][cc] = *(const f16x8*)&pps[(sj + jt * 16 + ln15) * 72 + cc * 32 + quad * 8];

    f32x4 oacc[4][4] = {};
    float m_run[2] = {-1e30f, -1e30f};
    float l_run[2] = {0.f, 0.f};

    for (int i0 = 0; i0 < L_DIM; i0 += 64) {
        __syncthreads();   // also orders k-frag reads before first pps overwrite
        for (int idx = tid; idx < 64 * 8; idx += 256) {
            int r = idx >> 3, c8 = idx & 7;
            *(float4*)&qTs[r * 72 + c8 * 8] = *(const float4*)&qb[(size_t)(i0 + r) * CQ_DIM + c8 * 8];
        }
        for (int idx = tid; idx < 128 * 8; idx += 256) {
            int r = idx >> 3, c8 = idx & 7;
            *(float4*)&vvs[r * 72 + c8 * 8] = *(const float4*)&vb[(size_t)(co0 + r) * L_DIM + i0 + c8 * 8];
        }
        __syncthreads();

        // scores: wave computes S[64i x 32j] at j = sj..sj+32
        f32x4 sacc[4][2] = {};
#pragma unroll
        for (int cc = 0; cc < 2; cc++) {
#pragma unroll
            for (int it = 0; it < 4; it++) {
                const f16x8 afr = *(const f16x8*)&qTs[(it * 16 + ln15) * 72 + cc * 32 + quad * 8];
                sacc[it][0] = __builtin_amdgcn_mfma_f32_16x16x32_f16(afr, kfr[0][cc], sacc[it][0], 0, 0, 0);
                sacc[it][1] = __builtin_amdgcn_mfma_f32_16x16x32_f16(afr, kfr[1][cc], sacc[it][1], 0, 0, 0);
            }
        }

        // online softmax update + p = exp2(s*log2e - m2) -> fp16 -> pps[j][i]
#pragma unroll
        for (int jt = 0; jt < 2; jt++) {
            const int j = sj + jt * 16 + ln15;
            float bm = -1e30f;
#pragma unroll
            for (int it = 0; it < 4; it++)
#pragma unroll
                for (int r = 0; r < 4; r++)
                    bm = fmaxf(bm, sacc[it][jt][r]);
            bm = fmaxf(bm, __shfl_xor(bm, 16, 64));
            bm = fmaxf(bm, __shfl_xor(bm, 32, 64));
            const float m_new = fmaxf(m_run[jt], bm);
            const float m2 = m_new * LOG2E;
            const float alpha = exp2f(m_run[jt] * LOG2E - m2);
            m_run[jt] = m_new;

            float lsum = 0.f;
#pragma unroll
            for (int it = 0; it < 4; it++) {
                float p0 = exp2f(fmaf(sacc[it][jt][0], LOG2E, -m2));
                float p1 = exp2f(fmaf(sacc[it][jt][1], LOG2E, -m2));
                float p2 = exp2f(fmaf(sacc[it][jt][2], LOG2E, -m2));
                float p3 = exp2f(fmaf(sacc[it][jt][3], LOG2E, -m2));
                lsum += (p0 + p1) + (p2 + p3);
                ushort4 r4;
                r4.x = f2h(p0); r4.y = f2h(p1); r4.z = f2h(p2); r4.w = f2h(p3);
                *(ushort4*)&pps[j * 72 + it * 16 + quad * 4] = r4;
            }
            lsum += __shfl_xor(lsum, 16, 64);
            lsum += __shfl_xor(lsum, 32, 64);
            l_run[jt] = l_run[jt] * alpha + lsum;
            if (quad == 0) al_s[j] = alpha;
        }
        __syncthreads();

        // PV: rescale O by alpha[j], then oacc += V[64co x 64i] * P[64i x 64j]
#pragma unroll
        for (int bb = 0; bb < 4; bb++) {
            const float a_bb = al_s[wj + bb * 16 + ln15];
#pragma unroll
            for (int a = 0; a < 4; a++)
#pragma unroll
                for (int r = 0; r < 4; r++)
                    oacc[a][bb][r] *= a_bb;
        }
#pragma unroll
        for (int cc = 0; cc < 2; cc++) {
            f16x8 afr[4], bfr[4];
#pragma unroll
            for (int t = 0; t < 4; t++)
                afr[t] = *(const f16x8*)&vvs[(wco + t * 16 + ln15) * 72 + cc * 32 + quad * 8];
#pragma unroll
            for (int t = 0; t < 4; t++)
                bfr[t] = *(const f16x8*)&pps[(wj + t * 16 + ln15) * 72 + cc * 32 + quad * 8];
#pragma unroll
            for (int a = 0; a < 4; a++)
#pragma unroll
                for (int bb = 0; bb < 4; bb++)
                    oacc[a][bb] = __builtin_amdgcn_mfma_f32_16x16x32_f16(afr[a], bfr[bb], oacc[a][bb], 0, 0, 0);
        }
    }

    __syncthreads();
    if (quad == 0) {
        al_s[sj + ln15] = l_run[0];
        al_s[sj + 16 + ln15] = l_run[1];
    }
    __syncthreads();

    const float g = gamma[0];
    float inv[4];
#pragma unroll
    for (int bb = 0; bb < 4; bb++)
        inv[bb] = g / al_s[wj + bb * 16 + ln15];

#pragma unroll
    for (int a = 0; a < 4; a++)
#pragma unroll
        for (int r = 0; r < 4; r++) {
            const int co = co0 + wco + a * 16 + quad * 4 + r;
            float* ob = out + ((size_t)b * C_DIM + co) * L_DIM + j0 + wj;
#pragma unroll
            for (int bb = 0; bb < 4; bb++)
                ob[bb * 16 + ln15] = oacc[a][bb][r] * inv[bb];
        }
}

// ---------------------------------------------------------------------------
extern "C" void kernel_launch(void* const* d_in, const int* in_sizes, int n_in,
                              void* d_out, int out_size, void* d_ws, size_t ws_size,
                              hipStream_t stream) {
    const float* x     = (const float*)d_in[0];
    const float* Wq    = (const float*)d_in[1];
    const float* Wk    = (const float*)d_in[2];
    const float* Wv    = (const float*)d_in[3];
    const float* gamma = (const float*)d_in[4];
    float* out = (float*)d_out;

    unsigned short* ws_h = (unsigned short*)d_ws;
    unsigned short* qT = ws_h;                        // 8*2048*64   = 1,048,576
    unsigned short* kT = qT + 1048576;
    unsigned short* vB = kT + 1048576;                // 8*512*2048  = 8,388,608
    unsigned short* xT = vB + 8388608;                // 8*2048*512  = 8,388,608
    unsigned short* Wh = xT + 8388608;                // 3*640*512   = 983,040

    prep_w  <<<3840, 256, 0, stream>>>(Wq, Wk, Wv, Wh);
    prep_x  <<<dim3(32, 8, 8), 256, 0, stream>>>(x, xT);
    conv_all<<<dim3(16, 10, 8), 256, 0, stream>>>(Wh, xT, qT, kT, vB);
    pv_k    <<<dim3(16, 4, 8), 256, 0, stream>>>(qT, kT, vB, gamma, out);
}

// Round 8
// 272.677 us; speedup vs baseline: 1.0820x; 1.0820x over previous
//
#include <hip/hip_runtime.h>
#include <cstddef>
#include <math.h>

#define L_DIM 2048
#define C_DIM 512
#define CQ_DIM 64
#define B_DIM 8

typedef _Float16 f16x8 __attribute__((ext_vector_type(8)));
typedef __fp16 fp16x2_t __attribute__((ext_vector_type(2)));
typedef float f32x4 __attribute__((ext_vector_type(4)));

__device__ __forceinline__ unsigned short f2h(float f) {
    union { _Float16 h; unsigned short u; } v;
    v.h = (_Float16)f;
    return v.u;
}

// packed fp32x2 -> fp16x2 (RTZ) as uint
__device__ __forceinline__ unsigned p2u(float a, float b) {
    union { fp16x2_t h; unsigned u; } v;
    v.h = __builtin_amdgcn_cvt_pkrtz(a, b);
    return v.u;
}

// ---------------------------------------------------------------------------
// prep_w: Wq/Wk/Wv (fp32 [co][ci][3]) -> Wh fp16 [t][640co][512ci]
// ---------------------------------------------------------------------------
__global__ __launch_bounds__(256) void prep_w(const float* __restrict__ Wq,
                                              const float* __restrict__ Wk,
                                              const float* __restrict__ Wv,
                                              unsigned short* __restrict__ Wh) {
    const int idx = blockIdx.x * 256 + threadIdx.x;
    const int ci = idx & 511;
    const int co = (idx >> 9) % 640;
    const int t  = idx / (640 * 512);
    float w;
    if (co < 64)       w = Wq[(size_t)co * 1536 + ci * 3 + t];
    else if (co < 128) w = Wk[(size_t)(co - 64) * 1536 + ci * 3 + t];
    else               w = Wv[(size_t)(co - 128) * 1536 + ci * 3 + t];
    Wh[idx] = f2h(w);
}

// ---------------------------------------------------------------------------
// prep_x: x fp32 [b][ci][l] -> xT fp16 [b][l][512ci]. 64ci x 64l tile per block.
// ---------------------------------------------------------------------------
__global__ __launch_bounds__(256) void prep_x(const float* __restrict__ x,
                                              unsigned short* __restrict__ xT) {
    const int l0  = blockIdx.x * 64;
    const int ci0 = blockIdx.y * 64;
    const int b   = blockIdx.z;

    __shared__ float xs[64][68];
    const int tid = threadIdx.x;
    const float* xb = x + ((size_t)b * C_DIM + ci0) * L_DIM;

    for (int idx = tid; idx < 64 * 16; idx += 256) {
        int ci = idx >> 4, lq = idx & 15;
        *(float4*)&xs[ci][lq * 4] = *(const float4*)&xb[(size_t)ci * L_DIM + l0 + lq * 4];
    }
    __syncthreads();

    unsigned short* ob = xT + ((size_t)b * L_DIM + l0) * C_DIM + ci0;
    for (int idx = tid; idx < 64 * 8; idx += 256) {
        int l = idx >> 3, c8 = idx & 7;
        ushort4 r0, r1;
        r0.x = f2h(xs[c8 * 8 + 0][l]); r0.y = f2h(xs[c8 * 8 + 1][l]);
        r0.z = f2h(xs[c8 * 8 + 2][l]); r0.w = f2h(xs[c8 * 8 + 3][l]);
        r1.x = f2h(xs[c8 * 8 + 4][l]); r1.y = f2h(xs[c8 * 8 + 5][l]);
        r1.z = f2h(xs[c8 * 8 + 6][l]); r1.w = f2h(xs[c8 * 8 + 7][l]);
        *(ushort4*)&ob[(size_t)l * C_DIM + c8 * 8] = r0;
        *(ushort4*)&ob[(size_t)l * C_DIM + c8 * 8 + 4] = r1;
    }
}

// ---------------------------------------------------------------------------
// conv_all: out[co,l] = sum_t sum_ci Wh[t][co][ci] * x[ci][l+t-1] via MFMA.
// ---------------------------------------------------------------------------
__global__ __launch_bounds__(256) void conv_all(const unsigned short* __restrict__ Wh,
                                                const unsigned short* __restrict__ xT,
                                                unsigned short* __restrict__ qT,
                                                unsigned short* __restrict__ kT,
                                                unsigned short* __restrict__ vB) {
    const int l0  = blockIdx.x * 128;
    const int co0 = blockIdx.y * 64;
    const int b   = blockIdx.z;

    __shared__ unsigned short As[3][64][40];
    __shared__ unsigned short Bs[130][40];

    const int tid  = threadIdx.x;
    const int lane = tid & 63, w = tid >> 6;
    const int ln15 = lane & 15, quad = lane >> 4;

    const int co_w = (w & 1) * 32;
    const int l_w  = (w >> 1) * 64;

    const unsigned short* xb = xT + (size_t)b * L_DIM * C_DIM;

    f32x4 acc[2][4] = {};

    for (int ci0 = 0; ci0 < C_DIM; ci0 += 32) {
        __syncthreads();
        for (int idx = tid; idx < 768; idx += 256) {
            int t = idx >> 8, co = (idx >> 2) & 63, c8 = idx & 3;
            *(float4*)&As[t][co][c8 * 8] =
                *(const float4*)&Wh[(((size_t)t * 640) + co0 + co) * C_DIM + ci0 + c8 * 8];
        }
        for (int idx = tid; idx < 520; idx += 256) {
            int la = idx >> 2, c8 = idx & 3;
            int l = l0 - 1 + la;
            float4 vx = {0.f, 0.f, 0.f, 0.f};
            if (l >= 0 && l < L_DIM)
                vx = *(const float4*)&xb[(size_t)l * C_DIM + ci0 + c8 * 8];
            *(float4*)&Bs[la][c8 * 8] = vx;
        }
        __syncthreads();

#pragma unroll
        for (int t = 0; t < 3; t++) {
            f16x8 a[2], bfr[4];
#pragma unroll
            for (int ct = 0; ct < 2; ct++)
                a[ct] = *(const f16x8*)&As[t][co_w + ct * 16 + ln15][quad * 8];
#pragma unroll
            for (int lt = 0; lt < 4; lt++)
                bfr[lt] = *(const f16x8*)&Bs[l_w + lt * 16 + ln15 + t][quad * 8];
#pragma unroll
            for (int ct = 0; ct < 2; ct++)
#pragma unroll
                for (int lt = 0; lt < 4; lt++)
                    acc[ct][lt] = __builtin_amdgcn_mfma_f32_16x16x32_f16(a[ct], bfr[lt], acc[ct][lt], 0, 0, 0);
        }
    }

    if (co0 < 128) {
        unsigned short* dst = (co0 == 0 ? qT : kT) + (size_t)b * L_DIM * CQ_DIM;
#pragma unroll
        for (int ct = 0; ct < 2; ct++)
#pragma unroll
            for (int lt = 0; lt < 4; lt++) {
                const int l = l0 + l_w + lt * 16 + ln15;
                ushort4 r;
                r.x = f2h(acc[ct][lt][0]); r.y = f2h(acc[ct][lt][1]);
                r.z = f2h(acc[ct][lt][2]); r.w = f2h(acc[ct][lt][3]);
                *(ushort4*)&dst[(size_t)l * CQ_DIM + co_w + ct * 16 + quad * 4] = r;
            }
    } else {
        unsigned short* dst = vB + ((size_t)b * C_DIM + (co0 - 128)) * L_DIM;
#pragma unroll
        for (int ct = 0; ct < 2; ct++)
#pragma unroll
            for (int lt = 0; lt < 4; lt++) {
                const int l = l0 + l_w + lt * 16 + ln15;
#pragma unroll
                for (int r = 0; r < 4; r++) {
                    const int co = co_w + ct * 16 + quad * 4 + r;
                    dst[(size_t)co * L_DIM + l] = f2h(acc[ct][lt][r]);
                }
            }
    }
}

// ---------------------------------------------------------------------------
// Fused attention, online softmax. Block tile 64j x 256co (4 waves):
//  - scores phase: wave w computes S[64i x 16j] (j group = w*16), softmax for
//    its 16 j entirely in-wave (quad shuffles), writes unnormalized p (fp16).
//  - PV phase: wave w computes O[64co x 64j] for co group w*64.
// K-fragments (8 VGPR) hoisted; kT staging LDS aliased as pps. ~51 KB LDS.
// Grid (32 j, 2 co, 8 b).
// ---------------------------------------------------------------------------
__global__ __launch_bounds__(256) void pv_k(const unsigned short* __restrict__ qT,
                                            const unsigned short* __restrict__ kT,
                                            const unsigned short* __restrict__ vB,
                                            const float* __restrict__ gamma,
                                            float* __restrict__ out) {
    const int j0  = blockIdx.x * 64;
    const int co0 = blockIdx.y * 256;
    const int b   = blockIdx.z;

    __shared__ unsigned short pps[64 * 68];   // init: kT stage [j][c]; loop: p [j][i]
    __shared__ unsigned short qTs[64 * 68];   // [i][c]
    __shared__ unsigned short vvs[256 * 68];  // [co][i]
    __shared__ float al_s[64];                // per-iter alpha[j]; reused for l at end

    const int tid = threadIdx.x;
    const int lane = tid & 63, w = tid >> 6;
    const int ln15 = lane & 15, quad = lane >> 4;

    const unsigned short* qb = qT + (size_t)b * L_DIM * CQ_DIM;
    const unsigned short* kb = kT + (size_t)b * L_DIM * CQ_DIM;
    const unsigned short* vb = vB + (size_t)b * C_DIM * L_DIM;

    const int sj  = w * 16;   // scores phase: wave's 16-j group
    const int wco = w * 64;   // PV phase: wave's co group within 256

    // ---- stage kT once, hoist this wave's K-fragments (8 VGPRs) ----
    for (int idx = tid; idx < 64 * 8; idx += 256) {
        int r = idx >> 3, c8 = idx & 7;
        *(float4*)&pps[r * 68 + c8 * 8] = *(const float4*)&kb[(size_t)(j0 + r) * CQ_DIM + c8 * 8];
    }
    __syncthreads();
    f16x8 kfr[2];
#pragma unroll
    for (int cc = 0; cc < 2; cc++)
        kfr[cc] = *(const f16x8*)&pps[(sj + ln15) * 68 + cc * 32 + quad * 8];

    f32x4 oacc[4][4] = {};   // [co-tile][j-tile]
    float m_run = -1e30f;
    float l_run = 0.f;

    for (int i0 = 0; i0 < L_DIM; i0 += 64) {
        __syncthreads();   // orders k-frag reads / prior-iter pps reads before overwrite
        for (int idx = tid; idx < 64 * 8; idx += 256) {
            int r = idx >> 3, c8 = idx & 7;
            *(float4*)&qTs[r * 68 + c8 * 8] = *(const float4*)&qb[(size_t)(i0 + r) * CQ_DIM + c8 * 8];
        }
        for (int idx = tid; idx < 256 * 8; idx += 256) {
            int r = idx >> 3, c8 = idx & 7;
            *(float4*)&vvs[r * 68 + c8 * 8] = *(const float4*)&vb[(size_t)(co0 + r) * L_DIM + i0 + c8 * 8];
        }
        __syncthreads();

        // scores: S[64i x 16j] for this wave's j group
        f32x4 sacc[4] = {};
#pragma unroll
        for (int cc = 0; cc < 2; cc++) {
#pragma unroll
            for (int it = 0; it < 4; it++) {
                const f16x8 afr = *(const f16x8*)&qTs[(it * 16 + ln15) * 68 + cc * 32 + quad * 8];
                sacc[it] = __builtin_amdgcn_mfma_f32_16x16x32_f16(afr, kfr[cc], sacc[it], 0, 0, 0);
            }
        }

        // online softmax for j = sj + ln15 (lane-column), i across quads
        const int j = sj + ln15;
        float bm = -1e30f;
#pragma unroll
        for (int it = 0; it < 4; it++)
#pragma unroll
            for (int r = 0; r < 4; r++)
                bm = fmaxf(bm, sacc[it][r]);
        bm = fmaxf(bm, __shfl_xor(bm, 16, 64));
        bm = fmaxf(bm, __shfl_xor(bm, 32, 64));
        const float m_new = fmaxf(m_run, bm);
        const float alpha = __expf(m_run - m_new);
        m_run = m_new;

        float lsum = 0.f;
#pragma unroll
        for (int it = 0; it < 4; it++) {
            float p0 = __expf(sacc[it][0] - m_new);
            float p1 = __expf(sacc[it][1] - m_new);
            float p2 = __expf(sacc[it][2] - m_new);
            float p3 = __expf(sacc[it][3] - m_new);
            lsum += (p0 + p1) + (p2 + p3);
            uint2 u;
            u.x = p2u(p0, p1);
            u.y = p2u(p2, p3);
            *(uint2*)&pps[j * 68 + it * 16 + quad * 4] = u;
        }
        lsum += __shfl_xor(lsum, 16, 64);
        lsum += __shfl_xor(lsum, 32, 64);
        l_run = l_run * alpha + lsum;
        if (quad == 0) al_s[j] = alpha;
        __syncthreads();

        // PV: rescale O by alpha[j] (skip when all 1), then
        // oacc += V[64co x 64i] * P[64i x 64j]
        float a_j[4];
#pragma unroll
        for (int bb = 0; bb < 4; bb++) a_j[bb] = al_s[bb * 16 + ln15];
        if (__any(a_j[0] < 1.f || a_j[1] < 1.f || a_j[2] < 1.f || a_j[3] < 1.f)) {
#pragma unroll
            for (int bb = 0; bb < 4; bb++)
#pragma unroll
                for (int a = 0; a < 4; a++)
#pragma unroll
                    for (int r = 0; r < 4; r++)
                        oacc[a][bb][r] *= a_j[bb];
        }
#pragma unroll
        for (int cc = 0; cc < 2; cc++) {
            f16x8 afr[4], bfr[4];
#pragma unroll
            for (int t = 0; t < 4; t++)
                afr[t] = *(const f16x8*)&vvs[(wco + t * 16 + ln15) * 68 + cc * 32 + quad * 8];
#pragma unroll
            for (int t = 0; t < 4; t++)
                bfr[t] = *(const f16x8*)&pps[(t * 16 + ln15) * 68 + cc * 32 + quad * 8];
#pragma unroll
            for (int a = 0; a < 4; a++)
#pragma unroll
                for (int bb = 0; bb < 4; bb++)
                    oacc[a][bb] = __builtin_amdgcn_mfma_f32_16x16x32_f16(afr[a], bfr[bb], oacc[a][bb], 0, 0, 0);
        }
    }

    // publish l (reuse al_s), then normalized epilogue
    __syncthreads();
    if (quad == 0) al_s[sj + ln15] = l_run;
    __syncthreads();

    const float g = gamma[0];
    float inv[4];
#pragma unroll
    for (int bb = 0; bb < 4; bb++)
        inv[bb] = g / al_s[bb * 16 + ln15];

#pragma unroll
    for (int a = 0; a < 4; a++)
#pragma unroll
        for (int r = 0; r < 4; r++) {
            const int co = co0 + wco + a * 16 + quad * 4 + r;
            float* ob = out + ((size_t)b * C_DIM + co) * L_DIM + j0;
#pragma unroll
            for (int bb = 0; bb < 4; bb++)
                ob[bb * 16 + ln15] = oacc[a][bb][r] * inv[bb];
        }
}

// ---------------------------------------------------------------------------
extern "C" void kernel_launch(void* const* d_in, const int* in_sizes, int n_in,
                              void* d_out, int out_size, void* d_ws, size_t ws_size,
                              hipStream_t stream) {
    const float* x     = (const float*)d_in[0];
    const float* Wq    = (const float*)d_in[1];
    const float* Wk    = (const float*)d_in[2];
    const float* Wv    = (const float*)d_in[3];
    const float* gamma = (const float*)d_in[4];
    float* out = (float*)d_out;

    unsigned short* ws_h = (unsigned short*)d_ws;
    unsigned short* qT = ws_h;                        // 8*2048*64   = 1,048,576
    unsigned short* kT = qT + 1048576;
    unsigned short* vB = kT + 1048576;                // 8*512*2048  = 8,388,608
    unsigned short* xT = vB + 8388608;                // 8*2048*512  = 8,388,608
    unsigned short* Wh = xT + 8388608;                // 3*640*512   = 983,040

    prep_w  <<<3840, 256, 0, stream>>>(Wq, Wk, Wv, Wh);
    prep_x  <<<dim3(32, 8, 8), 256, 0, stream>>>(x, xT);
    conv_all<<<dim3(16, 10, 8), 256, 0, stream>>>(Wh, xT, qT, kT, vB);
    pv_k    <<<dim3(32, 2, 8), 256, 0, stream>>>(qT, kT, vB, gamma, out);
}